// Round 15
// baseline (167.410 us; speedup 1.0000x reference)
//
#include <hip/hip_runtime.h>
#include <hip/hip_fp16.h>
#include <math.h>

// Problem constants
#define BB 8
#define CC 64
#define HH 128
#define WW 128
#define KK 6

// Workspace layout (float offsets). Total 794,688 floats = 3.18 MB.
#define FEAT_OFF 0                      // [B][1024]
#define COEF_OFF 8192                   // [N=48][C=64][S=2][H=128] = 786432

// Radon LDS geometry: CHANNEL-PAIR packed fp16 image. word(r,c) =
// {f16 imgA[r][c], f16 imgB[r][c]} in SHIFTED coords (r'=r+2, c'=c+2),
// rows/cols 0..131, stride 132. Interior at 2..129; borders zero.
// 132*132*4B = 69.7 KB. One bilinear sample-PAIR (both channels) =
// 2x ds_read2_b32 + packed-fp16 lerp: address/weight VALU shared by
// both channels (the 64 channels of a batch share ALL geometry).
#define PSTR 132
#define PIMG (PSTR * PSTR)             // 17424 words
#define PBASE 0                        // coords passed pre-shifted (+2)

typedef __fp16   h2  __attribute__((ext_vector_type(2)));  // cvt_pkrtz result
typedef _Float16 hf2 __attribute__((ext_vector_type(2)));  // packed fp16 math

// ---------------------------------------------------------------------------
// Kernel 1: adaptive avg-pool 4x4 -> feat[b, c*16 + i*4 + j]
// ---------------------------------------------------------------------------
__global__ __launch_bounds__(256) void k_pool(const float* __restrict__ x,
                                              float* __restrict__ ws) {
    int bc = blockIdx.x;               // b*64 + c
    int b = bc >> 6, c = bc & 63;
    int t = threadIdx.x;
    __shared__ float pool_l[16];
    if (t < 16) pool_l[t] = 0.f;
    __syncthreads();
    const float4* img4 = (const float4*)(x + (size_t)bc * 16384);
    float acc[4] = {0.f, 0.f, 0.f, 0.f};
    int cb = (t & 31) >> 3;            // W-block (32 float4 per row, 8 per block)
    #pragma unroll
    for (int r = 0; r < 16; ++r) {
        float4 v = img4[r * 256 + t];
        acc[r >> 2] += (v.x + v.y) + (v.z + v.w);
    }
    #pragma unroll
    for (int rb = 0; rb < 4; ++rb)
        atomicAdd(&pool_l[rb * 4 + cb], acc[rb]);
    __syncthreads();
    if (t < 16)
        ws[FEAT_OFF + b * 1024 + c * 16 + t] = pool_l[t] * (1.0f / 1024.0f);
}

// One bilinear sample-PAIR (channels A,B simultaneously). Direct imgp[]
// (__shared__) indexing -> ds_read2_b32 pairs: (idx,idx+132) and
// (idx+1,idx+133). Lerp in packed fp16 (v_pk_*), accumulate per-channel
// in fp32. Address + weights computed ONCE for both channels.
#define SAMPLEP(RR, CC, AA, AB) do {                               \
    float fr_ = floorf(RR), fc_ = floorf(CC);                      \
    float wr_ = (RR) - fr_, wc_ = (CC) - fc_;                      \
    hf2 wc2_ = __builtin_bit_cast(hf2, __builtin_amdgcn_cvt_pkrtz(wc_, wc_)); \
    hf2 wr2_ = __builtin_bit_cast(hf2, __builtin_amdgcn_cvt_pkrtz(wr_, wr_)); \
    int idx_ = (int)fmaf(fr_, 132.f, fc_);                         \
    hf2 l0_ = __builtin_bit_cast(hf2, imgp[idx_]);                 \
    hf2 l1_ = __builtin_bit_cast(hf2, imgp[idx_ + PSTR]);          \
    hf2 r0_ = __builtin_bit_cast(hf2, imgp[idx_ + 1]);             \
    hf2 r1_ = __builtin_bit_cast(hf2, imgp[idx_ + PSTR + 1]);      \
    hf2 top_ = l0_ + wc2_ * (r0_ - l0_);                           \
    hf2 bot_ = l1_ + wc2_ * (r1_ - l1_);                           \
    hf2 mid_ = top_ + wr2_ * (bot_ - top_);                        \
    AA += (float)mid_.x;                                           \
    AB += (float)mid_.y;                                           \
} while (0)

// exact per-lane sample interval [wA,wB] (slab estimate + serial verify);
// guarantees every sampled w has ix,iy in [-1,128] (original coords) ->
// shifted coords in [1,130], taps within the padded 132x132 image.
__device__ __forceinline__ void line_bounds(float co, float si, float ix0,
                                            float iy0, int& wA, int& wB) {
    float ic = 1.0f / co, is = 1.0f / (-si);
    float a1 = (-1.0f - ix0) * ic, a2 = (128.0f - ix0) * ic;
    float b1 = (-1.0f - iy0) * is, b2 = (128.0f - iy0) * is;
    float wlo = fmaxf(fminf(a1, a2), fminf(b1, b2));
    float whi = fminf(fmaxf(a1, a2), fmaxf(b1, b2));
    wA = max((int)ceilf(fmaxf(fminf(wlo, 200.f), -200.f)), 0);
    wB = min((int)floorf(fmaxf(fminf(whi, 200.f), -200.f)), 127);
    while (wA <= wB) {
        float cx = fmaf((float)wA, co, ix0), ry = fmaf((float)wA, -si, iy0);
        if (cx >= -1.f && cx <= 128.f && ry >= -1.f && ry <= 128.f) break;
        ++wA;
    }
    while (wB >= wA) {
        float cx = fmaf((float)wB, co, ix0), ry = fmaf((float)wB, -si, iy0);
        if (cx >= -1.f && cx <= 128.f && ry >= -1.f && ry <= 128.f) break;
        --wB;
    }
}

// ---------------------------------------------------------------------------
// Kernel 2: fused MLP (angles) + Radon + Wavelet, CHANNEL-PAIRED.
// Grid 512 = (b, channel-pair j of 32, angle-half ha of 2). Block handles
// channels {2j, 2j+1} x angles {3ha..3ha+2}. 512 threads, ~77 KB LDS ->
// 2 blocks/CU. Work split: 3 rounds; round q = angle 3ha+q, 128 lines x
// 4 quarter-lines (R4-verified structure), each unit sampling BOTH
// channels via SAMPLEP. Address/weight VALU is amortized 2x vs the
// per-channel kernel (theory: VALU-issue-dominated at ~50 cy/sample).
// ---------------------------------------------------------------------------
__global__ __launch_bounds__(512)
void k_radon(const float* __restrict__ x,
             const float* __restrict__ lin1_w,
             const float* __restrict__ lin1_b,
             const float* __restrict__ lin2_w,
             const float* __restrict__ lin2_b,
             const float* __restrict__ wf0,
             const float* __restrict__ wf1,
             float* __restrict__ ws) {
    int blk = blockIdx.x;
    int b = blk >> 6, j = (blk >> 1) & 31, ha = blk & 1;
    int t = threadIdx.x;
    __shared__ unsigned imgp[PIMG];    // 69.7 KB channel-pair image
    __shared__ float sigl[768];        // [r=2q+ch][h]: rows 0..5
    __shared__ float feat_l[8 * 132];  // padded stride 132 -> bank-clean MLP
    __shared__ float h_l[32];
    __shared__ float ang_l[6], ang_s[6];
    __shared__ float co_l[6], si_l[6];

    // --- zero borders: rows 0,1,130,131 full; cols 0,1,130,131 of 2..129 ---
    for (int i = t; i < 2 * PSTR; i += 512) {
        imgp[i] = 0u;                          // rows 0,1
        imgp[130 * PSTR + i] = 0u;             // rows 130,131
    }
    {
        int r = 2 + (t >> 2), sel = t & 3;     // 512 threads: rows 2..129 x 4
        int col = (sel < 2) ? sel : (128 + sel);
        imgp[r * PSTR + col] = 0u;
    }
    // --- stage interior: word(r', c') = {f16 A[r][c], f16 B[r][c]} ---
    const float4* A4 = (const float4*)(x + (size_t)((b << 6) + (j << 1)) * 16384);
    const float4* B4 = A4 + 4096;
    for (int i = t; i < 4096; i += 512) {
        float4 va = A4[i], vb = B4[i];
        int m4 = i & 31, row = i >> 5;
        unsigned* d = imgp + (row + 2) * PSTR + (m4 << 2) + 2;
        d[0] = __builtin_bit_cast(unsigned, __builtin_amdgcn_cvt_pkrtz(va.x, vb.x));
        d[1] = __builtin_bit_cast(unsigned, __builtin_amdgcn_cvt_pkrtz(va.y, vb.y));
        d[2] = __builtin_bit_cast(unsigned, __builtin_amdgcn_cvt_pkrtz(va.z, vb.z));
        d[3] = __builtin_bit_cast(unsigned, __builtin_amdgcn_cvt_pkrtz(va.w, vb.w));
    }
    // --- inline MLP: feat -> angles (first 256 threads) ---
    const float* feat = ws + FEAT_OFF + b * 1024;
    for (int i = t; i < 1024; i += 512)
        feat_l[(i >> 7) * 132 + (i & 127)] = feat[i];
    __syncthreads();
    if (t < 256) {
        int m = t >> 3, part = t & 7;
        const float4* wrow = (const float4*)(lin1_w + m * 1024 + part * 128);
        const float4* frow = (const float4*)(feat_l + part * 132);
        float acc = 0.f;
        #pragma unroll 8
        for (int i = 0; i < 32; ++i) {
            float4 wv = wrow[i], fv = frow[i];
            acc = fmaf(wv.x, fv.x, acc); acc = fmaf(wv.y, fv.y, acc);
            acc = fmaf(wv.z, fv.z, acc); acc = fmaf(wv.w, fv.w, acc);
        }
        acc += __shfl_xor(acc, 1);
        acc += __shfl_xor(acc, 2);
        acc += __shfl_xor(acc, 4);
        if (part == 0) h_l[m] = fmaxf(acc + lin1_b[m], 0.f);
    }
    __syncthreads();
    if (t < 6) {
        float a = lin2_b[t];
        #pragma unroll
        for (int i = 0; i < 32; ++i) a = fmaf(h_l[i], lin2_w[t * 32 + i], a);
        a = 36.0f * (float)t + a * 30.0f;          // base = linspace(0,180,6)
        ang_l[t] = fminf(fmaxf(a, 0.f), 180.f);
    }
    __syncthreads();
    if (t == 0) {
        float v[6];
        #pragma unroll
        for (int i = 0; i < 6; ++i) v[i] = ang_l[i];
        for (int i = 1; i < 6; ++i) {              // insertion sort
            float key = v[i]; int jj = i - 1;
            while (jj >= 0 && v[jj] > key) { v[jj + 1] = v[jj]; --jj; }
            v[jj + 1] = key;
        }
        #pragma unroll
        for (int i = 0; i < 6; ++i) ang_s[i] = v[i];
    }
    __syncthreads();
    if (t < 6) {
        float th = ang_s[t] * (3.14159265358979323846f / 180.0f);
        co_l[t] = cosf(th);
        si_l[t] = sinf(th);
    }
    __syncthreads();

    // sum sample-pairs over w in [sA,sB]; 4 independent chains, dual accs.
    auto radon_line2 = [&](float co, float si, float ix0s, float iy0s,
                           int sA, int sB, float& oA, float& oB) {
        float a0A = 0.f, a1A = 0.f, a2A = 0.f, a3A = 0.f;
        float a0B = 0.f, a1B = 0.f, a2B = 0.f, a3B = 0.f;
        int n = sB - sA + 1;
        if (n > 0) {
            float rr0 = fmaf((float)sA, -si, iy0s);
            float cc0 = fmaf((float)sA,  co, ix0s);
            float rr1 = rr0 - si, cc1 = cc0 + co;
            float rr2 = rr1 - si, cc2 = cc1 + co;
            float rr3 = rr2 - si, cc3 = cc2 + co;
            float si4 = 4.0f * si, co4 = 4.0f * co;
            int i = n;
            while (i >= 4) {
                SAMPLEP(rr0, cc0, a0A, a0B);
                SAMPLEP(rr1, cc1, a1A, a1B);
                SAMPLEP(rr2, cc2, a2A, a2B);
                SAMPLEP(rr3, cc3, a3A, a3B);
                rr0 -= si4; cc0 += co4;
                rr1 -= si4; cc1 += co4;
                rr2 -= si4; cc2 += co4;
                rr3 -= si4; cc3 += co4;
                i -= 4;
            }
            if (i > 0) SAMPLEP(rr0, cc0, a0A, a0B);
            if (i > 1) SAMPLEP(rr1, cc1, a1A, a1B);
            if (i > 2) SAMPLEP(rr2, cc2, a2A, a2B);
        }
        oA = (a0A + a1A) + (a2A + a3A);
        oB = (a0B + a1B) + (a2B + a3B);
    };

    // --- Radon: 3 rounds, one angle each; 128 lines x 4 quarter-lines.
    // Quarters of a line sit in 4 consecutive lanes -> shfl_xor merge. ---
    int ha3 = ha * 3;
    #pragma unroll 1
    for (int q = 0; q < 3; ++q) {
        int h = t >> 2, qt = t & 3;
        int kg = ha3 + q;
        float co = co_l[kg], si = si_l[kg];
        float yc = fmaf((float)h, 2.0f / 127.0f, -1.0f);
        float ix0 = (fmaf(yc, si, -co) + 1.0f) * 63.5f;  // col; d/dw = +co
        float iy0 = (fmaf(yc, co,  si) + 1.0f) * 63.5f;  // row; d/dw = -si
        int wA, wB;
        line_bounds(co, si, ix0, iy0, wA, wB);
        int len = wB - wA + 1; if (len < 0) len = 0;
        int s0 = wA + ((len * qt) >> 2);
        int s1 = wA + ((len * (qt + 1)) >> 2) - 1;
        float aA, aB;
        radon_line2(co, si, ix0 + 2.0f, iy0 + 2.0f, s0, s1, aA, aB);
        aA += __shfl_xor(aA, 1);
        aA += __shfl_xor(aA, 2);
        aB += __shfl_xor(aB, 1);
        aB += __shfl_xor(aB, 2);
        if (qt == 0) {
            sigl[(q << 8) + h] = aA;            // row 2q   (channel 2j)
            sigl[(q << 8) + 128 + h] = aB;      // row 2q+1 (channel 2j+1)
        }
    }
    __syncthreads();

    // --- Wavelet chain on sigl rows r=0..5 (r=2q+ch). Scratch overlays
    // imgp. Output indices: kg = ha3 + (r>>1), c = 2j + (r&1). ---
    float* scr = (float*)imgp;
    float* cur = scr;            // 6*64
    float* f1  = scr + 384;      // 6*64
    float* p1  = scr + 768;      // 6*32
    float* u1  = scr + 960;      // 6*64
    float g0 = wf0[0], g1 = wf0[1], g2 = wf0[2];
    int c2j = j << 1;

    for (int p = t; p < 768; p += 512) {           // c0 = conv3(sig)
        int r = p >> 7, h = p & 127;
        const float* s = sigl + r * 128;
        float sm1 = (h > 0)   ? s[h - 1] : 0.f;
        float sp1 = (h < 127) ? s[h + 1] : 0.f;
        float c0 = sm1 * g0 + s[h] * g1 + sp1 * g2;
        int kg = ha3 + (r >> 1), cc = c2j + (r & 1);
        ws[COEF_OFF + (((b * 6 + kg) * 64 + cc) * 2 + 0) * 128 + h] = c0;
    }
    for (int q = t; q < 384; q += 512) {           // cur = avgpool(sig)
        int r = q >> 6, l = q & 63;
        cur[q] = (sigl[r * 128 + 2 * l] + sigl[r * 128 + 2 * l + 1]) * 0.5f;
    }
    __syncthreads();

    float w10 = wf1[0], w11 = wf1[1], w12 = wf1[2], w13 = wf1[3], w14 = wf1[4];
    for (int q = t; q < 384; q += 512) {           // f1 = conv5(cur)
        int r = q >> 6, l = q & 63;
        const float* cu = cur + r * 64;
        float a = cu[l] * w12;
        a += (l >= 2)  ? cu[l - 2] * w10 : 0.f;
        a += (l >= 1)  ? cu[l - 1] * w11 : 0.f;
        a += (l <= 62) ? cu[l + 1] * w13 : 0.f;
        a += (l <= 61) ? cu[l + 2] * w14 : 0.f;
        f1[q] = a;
    }
    __syncthreads();

    for (int q = t; q < 192; q += 512) {           // p1 = avgpool(f1)
        int r = q >> 5, m = q & 31;
        p1[q] = (f1[r * 64 + 2 * m] + f1[r * 64 + 2 * m + 1]) * 0.5f;
    }
    __syncthreads();

    for (int q = t; q < 384; q += 512) {           // u1 = interp(p1: 32->64)
        int r = q >> 6, l = q & 63;
        float real = fminf(fmaxf(0.5f * (float)l - 0.25f, 0.f), 31.f);
        int i0 = (int)real;
        int i1 = min(i0 + 1, 31);
        float wv = real - (float)i0;
        u1[q] = p1[r * 32 + i0] * (1.f - wv) + p1[r * 32 + i1] * wv;
    }
    __syncthreads();

    for (int p = t; p < 768; p += 512) {           // c1 = interp(u1: 64->128)
        int r = p >> 7, h = p & 127;
        float real = fminf(fmaxf(0.5f * (float)h - 0.25f, 0.f), 63.f);
        int i0 = (int)real;
        int i1 = min(i0 + 1, 63);
        float wv = real - (float)i0;
        float c1 = u1[r * 64 + i0] * (1.f - wv) + u1[r * 64 + i1] * wv;
        int kg = ha3 + (r >> 1), cc = c2j + (r & 1);
        ws[COEF_OFF + (((b * 6 + kg) * 64 + cc) * 2 + 1) * 128 + h] = c1;
    }
}

// ---------------------------------------------------------------------------
// Kernel 3: fusion GEMM + BN affine + k(6)->w(128) align_corners=True
// interp + ReLU + store. S never hits HBM.
// grid 1024 = (b, oquad of 16 o's, j of 4 h2's); 256 threads =
// (cq(4) x op(16) x h2p(4)), each accumulates 32 c2 then LDS-reduces.
// ~28 KB LDS -> 4 blocks/CU resident.
// ---------------------------------------------------------------------------
__global__ __launch_bounds__(256, 4) void k_fuseout(const float* __restrict__ fuse_w,
                                                    const float* __restrict__ fuse_b,
                                                    const float* __restrict__ bn_gamma,
                                                    const float* __restrict__ bn_beta,
                                                    const float* __restrict__ bn_mean,
                                                    const float* __restrict__ bn_var,
                                                    const float* __restrict__ ws,
                                                    float* __restrict__ out) {
    int blk = blockIdx.x;
    int b = blk >> 7, oq = (blk >> 5) & 3, j = blk & 31;  // o in [16oq,16oq+16), h2 in [4j,4j+4)
    int t = threadIdx.x;
    __shared__ float M_l[6 * 128 * 4];   // [k][c2][h2p] 12 KB
    __shared__ float W_l[16 * 132];      // padded stride 132, 8.25 KB
    __shared__ float P_l[4 * 16 * 4 * 6];// [cq][op][h2p][k] partials, 6 KB
    __shared__ float S_l[16 * 4 * 6];    // [op][h2p][k] 1.5 KB

    // stage M with the torch .view permutation undone. For h2 = 4j + h2p:
    // s = h2&1, hh = h2>>1 in {2j, 2j+1}, hp = (c2&1)*64 + hh, c = c2>>1.
    for (int i = t; i < 1536; i += 256) {
        int half = i & 1, s = (i >> 1) & 1, cc = (i >> 2) & 63, k = i >> 8;
        const float* src = ws + COEF_OFF +
            (((b * 6 + k) * 64 + cc) * 2 + s) * 128 + half * 64 + 2 * j;
        float v0 = src[0], v1 = src[1];
        int c2 = 2 * cc + half;
        float* d = M_l + (k * 128 + c2) * 4;
        d[s] = v0;           // hh=2j   -> h2p = s
        d[2 + s] = v1;       // hh=2j+1 -> h2p = 2+s
    }
    for (int i = t; i < 2048; i += 256) {
        int op = i >> 7, c2 = i & 127;
        W_l[op * 132 + c2] = fuse_w[(oq * 16 + op) * 128 + c2];
    }
    __syncthreads();

    // GEMM partials: thread = (cq = t>>6, op = (t>>2)&15, h2p = t&3),
    // acc[k] over c2 in [32cq, 32cq+32)
    int cq = t >> 6, op = (t >> 2) & 15, h2p = t & 3;
    {
        float acc[6] = {0.f, 0.f, 0.f, 0.f, 0.f, 0.f};
        const float* wrow = W_l + op * 132 + cq * 32;
        const float* mbase = M_l + (cq * 32) * 4 + h2p;
        #pragma unroll 4
        for (int c2 = 0; c2 < 32; ++c2) {
            float wv = wrow[c2];
            const float* m = mbase + c2 * 4;
            #pragma unroll
            for (int k = 0; k < 6; ++k)
                acc[k] = fmaf(wv, m[k * 512], acc[k]);
        }
        float* prow = P_l + ((cq * 16 + op) * 4 + h2p) * 6;
        #pragma unroll
        for (int k = 0; k < 6; ++k)
            prow[k] = acc[k];
    }
    __syncthreads();

    // reduce the 4 cq-partials + BN affine (threads with cq==0, i.e. t<64)
    if (cq == 0) {
        int o = oq * 16 + op;
        float scale = bn_gamma[o] * rsqrtf(bn_var[o] + 1e-5f);
        float shift = (fuse_b[o] - bn_mean[o]) * scale + bn_beta[o];
        int base = (op * 4 + h2p) * 6;
        float* srow = S_l + base;
        #pragma unroll
        for (int k = 0; k < 6; ++k) {
            float v = P_l[base + k] + P_l[384 + base + k]
                    + P_l[768 + base + k] + P_l[1152 + base + k];
            srow[k] = fmaf(v, scale, shift);
        }
    }
    __syncthreads();

    // epilogue: k->w interp + relu + store. 16*4*128 = 8192 outs, 32/thread.
    for (int it = 0; it < 32; ++it) {
        int flat = it * 256 + t;
        int w = flat & 127, row = flat >> 7;       // row = op*4 + h2p (<64)
        float pos = (float)w * (5.0f / 127.0f);
        int i0 = min((int)pos, 5);
        int i1 = min(i0 + 1, 5);
        float tt = pos - (float)i0;
        const float* srow = S_l + row * 6;
        float val = srow[i0] * (1.f - tt) + srow[i1] * tt;
        int o = oq * 16 + (row >> 2);
        int h2 = 4 * j + (row & 3);
        out[(((b * 64 + o) * 128) + h2) * 128 + w] = fmaxf(val, 0.f);
    }
}

// ---------------------------------------------------------------------------
extern "C" void kernel_launch(void* const* d_in, const int* in_sizes, int n_in,
                              void* d_out, int out_size, void* d_ws, size_t ws_size,
                              hipStream_t stream) {
    const float* x        = (const float*)d_in[0];
    const float* lin1_w   = (const float*)d_in[1];
    const float* lin1_b   = (const float*)d_in[2];
    const float* lin2_w   = (const float*)d_in[3];
    const float* lin2_b   = (const float*)d_in[4];
    const float* wf0      = (const float*)d_in[5];
    const float* wf1      = (const float*)d_in[6];
    const float* fuse_w   = (const float*)d_in[7];
    const float* fuse_b   = (const float*)d_in[8];
    const float* bn_gamma = (const float*)d_in[9];
    const float* bn_beta  = (const float*)d_in[10];
    const float* bn_mean  = (const float*)d_in[11];
    const float* bn_var   = (const float*)d_in[12];
    float* ws  = (float*)d_ws;        // needs 3.18 MB
    float* out = (float*)d_out;

    hipLaunchKernelGGL(k_pool,    dim3(BB * CC), dim3(256), 0, stream, x, ws);
    hipLaunchKernelGGL(k_radon,   dim3(BB * CC), dim3(512), 0, stream,
                       x, lin1_w, lin1_b, lin2_w, lin2_b, wf0, wf1, ws);
    hipLaunchKernelGGL(k_fuseout, dim3(1024),    dim3(256), 0, stream,
                       fuse_w, fuse_b, bn_gamma, bn_beta, bn_mean, bn_var,
                       ws, out);
}

// Round 16
// 162.054 us; speedup vs baseline: 1.0331x; 1.0331x over previous
//
#include <hip/hip_runtime.h>
#include <hip/hip_fp16.h>
#include <math.h>

// Problem constants
#define BB 8
#define CC 64
#define HH 128
#define WW 128
#define KK 6

// Workspace layout (float offsets). Total 794,688 floats = 3.18 MB.
#define FEAT_OFF 0                      // [B][1024]
#define COEF_OFF 8192                   // [N=48][C=64][S=2][H=128] = 786432

// Radon LDS geometry: fp16 PAIR-PACKED image. word(r,c) = {img[r][c],
// img[r][c+1]}, rows r in -2..129, word cols c in -2..130, stride 133 words.
// One bilinear sample = ONE ds_read2_b32 (words at (r0,c0),(r0+1,c0)).
#define WSTR 133
#define NROW 132
#define IMGW (NROW * WSTR)             // 17556 words = 70.2 KB
#define IBASE (2 * WSTR + 2)           // word index of (r=0,c=0)

typedef __fp16   h2  __attribute__((ext_vector_type(2)));  // storage / cvt_pkrtz
typedef _Float16 hf2 __attribute__((ext_vector_type(2)));  // fdot2 operand type

#if __has_builtin(__builtin_amdgcn_fdot2)
#define FDOT2(A, B) __builtin_amdgcn_fdot2(__builtin_bit_cast(hf2, (A)), \
                                           __builtin_bit_cast(hf2, (B)), 0.f, false)
#define FDOT2A(A, B, C) __builtin_amdgcn_fdot2(__builtin_bit_cast(hf2, (A)), \
                                               __builtin_bit_cast(hf2, (B)), (C), false)
#define HAVE_FDOT2 1
#endif

// ---------------------------------------------------------------------------
// Kernel 1: adaptive avg-pool 4x4 -> feat[b, c*16 + i*4 + j]
// ---------------------------------------------------------------------------
__global__ __launch_bounds__(256) void k_pool(const float* __restrict__ x,
                                              float* __restrict__ ws) {
    int bc = blockIdx.x;               // b*64 + c
    int b = bc >> 6, c = bc & 63;
    int t = threadIdx.x;
    __shared__ float pool_l[16];
    if (t < 16) pool_l[t] = 0.f;
    __syncthreads();
    const float4* img4 = (const float4*)(x + (size_t)bc * 16384);
    float acc[4] = {0.f, 0.f, 0.f, 0.f};
    int cb = (t & 31) >> 3;            // W-block (32 float4 per row, 8 per block)
    #pragma unroll
    for (int r = 0; r < 16; ++r) {
        float4 v = img4[r * 256 + t];
        acc[r >> 2] += (v.x + v.y) + (v.z + v.w);
    }
    #pragma unroll
    for (int rb = 0; rb < 4; ++rb)
        atomicAdd(&pool_l[rb * 4 + cb], acc[rb]);
    __syncthreads();
    if (t < 16)
        ws[FEAT_OFF + b * 1024 + c * 16 + t] = pool_l[t] * (1.0f / 1024.0f);
}

// One bilinear sample: 1 ds_read2_b32 + packed-fp16 dot-product consume.
// Direct __shared__ indexing (addrspace(3) GEP -> ds_read2_b32 verified).
#ifdef HAVE_FDOT2
#define SAMPLED(RR, CC, ACC) do {                                  \
    float fr_ = floorf(RR), fc_ = floorf(CC);                      \
    float wr_ = (RR) - fr_, wc_ = (CC) - fc_;                      \
    h2 wv_ = __builtin_amdgcn_cvt_pkrtz(1.0f - wc_, wc_);          \
    int idx_ = IBASE + (int)fmaf(fr_, 133.f, fc_);                 \
    h2 tp_ = imgh[idx_];                                           \
    h2 bt_ = imgh[idx_ + WSTR];                                    \
    float top_ = FDOT2(wv_, tp_);                                  \
    float d_ = FDOT2A(wv_, bt_, -top_);                            \
    ACC = fmaf(wr_, d_, ACC + top_);                               \
} while (0)
#else
#define SAMPLED(RR, CC, ACC) do {                                  \
    float fr_ = floorf(RR), fc_ = floorf(CC);                      \
    float wr_ = (RR) - fr_, wc_ = (CC) - fc_;                      \
    int idx_ = IBASE + (int)fmaf(fr_, 133.f, fc_);                 \
    h2 tp_ = imgh[idx_];                                           \
    h2 bt_ = imgh[idx_ + WSTR];                                    \
    float t0_ = fmaf(wc_, (float)tp_.y - (float)tp_.x, (float)tp_.x); \
    float t1_ = fmaf(wc_, (float)bt_.y - (float)bt_.x, (float)bt_.x); \
    ACC += fmaf(wr_, t1_ - t0_, t0_);                              \
} while (0)
#endif

// exact per-lane sample interval [wA,wB] (slab estimate + serial verify);
// guarantees every sampled w has ix,iy in [-1,128] -> taps in padded LDS.
__device__ __forceinline__ void line_bounds(float co, float si, float ix0,
                                            float iy0, int& wA, int& wB) {
    float ic = 1.0f / co, is = 1.0f / (-si);
    float a1 = (-1.0f - ix0) * ic, a2 = (128.0f - ix0) * ic;
    float b1 = (-1.0f - iy0) * is, b2 = (128.0f - iy0) * is;
    float wlo = fmaxf(fminf(a1, a2), fminf(b1, b2));
    float whi = fminf(fmaxf(a1, a2), fmaxf(b1, b2));
    wA = max((int)ceilf(fmaxf(fminf(wlo, 200.f), -200.f)), 0);
    wB = min((int)floorf(fmaxf(fminf(whi, 200.f), -200.f)), 127);
    while (wA <= wB) {
        float cx = fmaf((float)wA, co, ix0), ry = fmaf((float)wA, -si, iy0);
        if (cx >= -1.f && cx <= 128.f && ry >= -1.f && ry <= 128.f) break;
        ++wA;
    }
    while (wB >= wA) {
        float cx = fmaf((float)wB, co, ix0), ry = fmaf((float)wB, -si, iy0);
        if (cx >= -1.f && cx <= 128.f && ry >= -1.f && ry <= 128.f) break;
        --wB;
    }
}

// ---------------------------------------------------------------------------
// Kernel 2: fused MLP (angles) + Radon + Wavelet. One block per (b,c),
// 512 threads (8 waves), ~78 KB LDS -> 2 blocks/CU = 4 waves/SIMD.
// STRUCTURAL CEILING (measured over 7 intervention families, R0-R15):
// time is pinned by the dependent ds_read latency chain at ~34 cyc
// effective per DS instruction (~136 cyc latency / 4 waves). VALU (42-57%),
// LDS banks (~40%), and HBM (5-9%) all have slack; halving VALU
// (channel-pairing) and doubling occupancy both left time flat or worse.
// ---------------------------------------------------------------------------
__global__ __launch_bounds__(512)
__attribute__((amdgpu_waves_per_eu(4, 4)))
void k_radon(const float* __restrict__ x,
             const float* __restrict__ lin1_w,
             const float* __restrict__ lin1_b,
             const float* __restrict__ lin2_w,
             const float* __restrict__ lin2_b,
             const float* __restrict__ wf0,
             const float* __restrict__ wf1,
             float* __restrict__ ws) {
    int bc = blockIdx.x;
    int b = bc >> 6, c = bc & 63;
    int t = threadIdx.x;
    __shared__ h2 imgh[IMGW];          // 70.2 KB pair-packed image
    __shared__ float sigl[768];        // [k][h]
    __shared__ float feat_l[8 * 132];  // padded stride 132 -> bank-clean MLP
    __shared__ float h_l[32];
    __shared__ float ang_l[6], ang_s[6];
    __shared__ float co_l[6], si_l[6];

    const h2 z2 = {(__fp16)0.f, (__fp16)0.f};
    // --- zero border words (rows -2,-1,128,129 full; cols -2 and 128) ---
    for (int i = t; i < 2 * WSTR; i += 512) {
        imgh[i] = z2;
        imgh[130 * WSTR + i] = z2;
    }
    if (t < 128) {
        h2* r = imgh + (t + 2) * WSTR;
        r[0] = z2;                     // word c=-2
        r[130] = z2;                   // word c=128 = {img[128],img[129]} = 0
    }
    // --- stage interior, pair-packed: word(c) = {img[c], img[c+1]} ---
    const float4* src4 = (const float4*)(x + (size_t)bc * 16384);
    for (int i = t; i < 4096; i += 512) {
        float4 v = src4[i];
        float nxt = __shfl_down(v.x, 1);           // next float4's .x (lane+1)
        int j = i & 31, row = i >> 5;
        if (j == 31) nxt = 0.f;                    // col 128 -> zero pad
        h2* d = imgh + (row + 2) * WSTR + (j << 2) + 2;
        d[0] = __builtin_amdgcn_cvt_pkrtz(v.x, v.y);
        d[1] = __builtin_amdgcn_cvt_pkrtz(v.y, v.z);
        d[2] = __builtin_amdgcn_cvt_pkrtz(v.z, v.w);
        d[3] = __builtin_amdgcn_cvt_pkrtz(v.w, nxt);
        if (j == 0)                                // word c=-1 = {0, img[0]}
            imgh[(row + 2) * WSTR + 1] = __builtin_amdgcn_cvt_pkrtz(0.f, v.x);
    }
    // --- inline MLP: feat -> angles (first 256 threads) ---
    const float* feat = ws + FEAT_OFF + b * 1024;
    for (int i = t; i < 1024; i += 512)
        feat_l[(i >> 7) * 132 + (i & 127)] = feat[i];
    __syncthreads();
    if (t < 256) {
        int m = t >> 3, part = t & 7;
        const float4* wrow = (const float4*)(lin1_w + m * 1024 + part * 128);
        const float4* frow = (const float4*)(feat_l + part * 132);
        float acc = 0.f;
        #pragma unroll 8
        for (int i = 0; i < 32; ++i) {
            float4 wv = wrow[i], fv = frow[i];
            acc = fmaf(wv.x, fv.x, acc); acc = fmaf(wv.y, fv.y, acc);
            acc = fmaf(wv.z, fv.z, acc); acc = fmaf(wv.w, fv.w, acc);
        }
        acc += __shfl_xor(acc, 1);
        acc += __shfl_xor(acc, 2);
        acc += __shfl_xor(acc, 4);
        if (part == 0) h_l[m] = fmaxf(acc + lin1_b[m], 0.f);
    }
    __syncthreads();
    if (t < 6) {
        float a = lin2_b[t];
        #pragma unroll
        for (int i = 0; i < 32; ++i) a = fmaf(h_l[i], lin2_w[t * 32 + i], a);
        a = 36.0f * (float)t + a * 30.0f;          // base = linspace(0,180,6)
        ang_l[t] = fminf(fmaxf(a, 0.f), 180.f);
    }
    __syncthreads();
    if (t == 0) {
        float v[6];
        #pragma unroll
        for (int i = 0; i < 6; ++i) v[i] = ang_l[i];
        for (int i = 1; i < 6; ++i) {              // insertion sort
            float key = v[i]; int j = i - 1;
            while (j >= 0 && v[j] > key) { v[j + 1] = v[j]; --j; }
            v[j + 1] = key;
        }
        #pragma unroll
        for (int i = 0; i < 6; ++i) ang_s[i] = v[i];
    }
    __syncthreads();
    if (t < 6) {
        float th = ang_s[t] * (3.14159265358979323846f / 180.0f);
        co_l[t] = cosf(th);
        si_l[t] = sinf(th);
    }
    __syncthreads();

    // sum bilinear samples over w in [sA,sB]; 4 independent chains.
    auto radon_line = [&](float co, float si, float ix0, float iy0,
                          int sA, int sB) -> float {
        int n = sB - sA + 1;
        if (n <= 0) return 0.f;
        float rr0 = fmaf((float)sA, -si, iy0);
        float cc0 = fmaf((float)sA,  co, ix0);
        float rr1 = rr0 - si, cc1 = cc0 + co;
        float rr2 = rr1 - si, cc2 = cc1 + co;
        float rr3 = rr2 - si, cc3 = cc2 + co;
        float si4 = 4.0f * si, co4 = 4.0f * co;
        float a0 = 0.f, a1 = 0.f, a2 = 0.f, a3 = 0.f;
        int i = n;
        while (i >= 4) {
            SAMPLED(rr0, cc0, a0);
            SAMPLED(rr1, cc1, a1);
            SAMPLED(rr2, cc2, a2);
            SAMPLED(rr3, cc3, a3);
            rr0 -= si4; cc0 += co4;
            rr1 -= si4; cc1 += co4;
            rr2 -= si4; cc2 += co4;
            rr3 -= si4; cc3 += co4;
            i -= 4;
        }
        if (i > 0) SAMPLED(rr0, cc0, a0);  // chain heads already positioned
        if (i > 1) SAMPLED(rr1, cc1, a1);
        if (i > 2) SAMPLED(rr2, cc2, a2);
        return (a0 + a1) + (a2 + a3);
    };

    // --- Radon pass A: lines 0..511, one full line per thread ---
    {
        int p = t, k = p >> 7, h = p & 127;
        float co = co_l[k], si = si_l[k];
        float yc = fmaf((float)h, 2.0f / 127.0f, -1.0f);
        float ix0 = (fmaf(yc, si, -co) + 1.0f) * 63.5f;  // col; d/dw = +co
        float iy0 = (fmaf(yc, co,  si) + 1.0f) * 63.5f;  // row; d/dw = -si
        int wA, wB;
        line_bounds(co, si, ix0, iy0, wA, wB);
        sigl[p] = radon_line(co, si, ix0, iy0, wA, wB);
    }
    // --- Radon pass B: lines 512..767, half-line per thread (even/odd) ---
    {
        int p = 512 + (t >> 1), k = p >> 7, h = p & 127;
        int half = t & 1;
        float co = co_l[k], si = si_l[k];
        float yc = fmaf((float)h, 2.0f / 127.0f, -1.0f);
        float ix0 = (fmaf(yc, si, -co) + 1.0f) * 63.5f;
        float iy0 = (fmaf(yc, co,  si) + 1.0f) * 63.5f;
        int wA, wB;
        line_bounds(co, si, ix0, iy0, wA, wB);
        int mid = wA + ((wB - wA + 1) >> 1);
        int sA = half ? mid : wA;
        int sB = half ? wB : (mid - 1);
        float a = radon_line(co, si, ix0, iy0, sA, sB);
        a += __shfl_xor(a, 1);                     // merge the two halves
        if (half == 0) sigl[p] = a;
    }
    __syncthreads();

    // --- Wavelet chain on sigl (6 rows of 128). Scratch overlays imgh. ---
    float* scr = (float*)imgh;
    float* cur = scr;            // 6*64
    float* f1  = scr + 384;      // 6*64
    float* p1  = scr + 768;      // 6*32
    float* u1  = scr + 960;      // 6*64
    float g0 = wf0[0], g1 = wf0[1], g2 = wf0[2];

    for (int p = t; p < 768; p += 512) {           // c0 = conv3(sig)
        int k = p >> 7, h = p & 127;
        const float* s = sigl + k * 128;
        float sm1 = (h > 0)   ? s[h - 1] : 0.f;
        float sp1 = (h < 127) ? s[h + 1] : 0.f;
        float c0 = sm1 * g0 + s[h] * g1 + sp1 * g2;
        ws[COEF_OFF + (((b * 6 + k) * 64 + c) * 2 + 0) * 128 + h] = c0;
    }
    for (int q = t; q < 384; q += 512) {           // cur = avgpool(sig)
        int k = q >> 6, l = q & 63;
        cur[q] = (sigl[k * 128 + 2 * l] + sigl[k * 128 + 2 * l + 1]) * 0.5f;
    }
    __syncthreads();

    float w10 = wf1[0], w11 = wf1[1], w12 = wf1[2], w13 = wf1[3], w14 = wf1[4];
    for (int q = t; q < 384; q += 512) {           // f1 = conv5(cur)
        int k = q >> 6, l = q & 63;
        const float* cu = cur + k * 64;
        float a = cu[l] * w12;
        a += (l >= 2)  ? cu[l - 2] * w10 : 0.f;
        a += (l >= 1)  ? cu[l - 1] * w11 : 0.f;
        a += (l <= 62) ? cu[l + 1] * w13 : 0.f;
        a += (l <= 61) ? cu[l + 2] * w14 : 0.f;
        f1[q] = a;
    }
    __syncthreads();

    for (int q = t; q < 192; q += 512) {           // p1 = avgpool(f1)
        int k = q >> 5, m = q & 31;
        p1[q] = (f1[k * 64 + 2 * m] + f1[k * 64 + 2 * m + 1]) * 0.5f;
    }
    __syncthreads();

    for (int q = t; q < 384; q += 512) {           // u1 = interp(p1: 32->64)
        int k = q >> 6, l = q & 63;
        float real = fminf(fmaxf(0.5f * (float)l - 0.25f, 0.f), 31.f);
        int i0 = (int)real;
        int i1 = min(i0 + 1, 31);
        float wv = real - (float)i0;
        u1[q] = p1[k * 32 + i0] * (1.f - wv) + p1[k * 32 + i1] * wv;
    }
    __syncthreads();

    for (int p = t; p < 768; p += 512) {           // c1 = interp(u1: 64->128)
        int k = p >> 7, h = p & 127;
        float real = fminf(fmaxf(0.5f * (float)h - 0.25f, 0.f), 63.f);
        int i0 = (int)real;
        int i1 = min(i0 + 1, 63);
        float wv = real - (float)i0;
        float c1 = u1[k * 64 + i0] * (1.f - wv) + u1[k * 64 + i1] * wv;
        ws[COEF_OFF + (((b * 6 + k) * 64 + c) * 2 + 1) * 128 + h] = c1;
    }
}

// ---------------------------------------------------------------------------
// Kernel 3: fusion GEMM + BN affine + k(6)->w(128) align_corners=True
// interp + ReLU + store. S never hits HBM.
// grid 1024 = (b, oquad of 16 o's, j of 4 h2's); 256 threads =
// (cq(4) x op(16) x h2p(4)), each accumulates 32 c2 then LDS-reduces.
// ~28 KB LDS -> 4 blocks/CU resident.
// ---------------------------------------------------------------------------
__global__ __launch_bounds__(256, 4) void k_fuseout(const float* __restrict__ fuse_w,
                                                    const float* __restrict__ fuse_b,
                                                    const float* __restrict__ bn_gamma,
                                                    const float* __restrict__ bn_beta,
                                                    const float* __restrict__ bn_mean,
                                                    const float* __restrict__ bn_var,
                                                    const float* __restrict__ ws,
                                                    float* __restrict__ out) {
    int blk = blockIdx.x;
    int b = blk >> 7, oq = (blk >> 5) & 3, j = blk & 31;  // o in [16oq,16oq+16), h2 in [4j,4j+4)
    int t = threadIdx.x;
    __shared__ float M_l[6 * 128 * 4];   // [k][c2][h2p] 12 KB
    __shared__ float W_l[16 * 132];      // padded stride 132, 8.25 KB
    __shared__ float P_l[4 * 16 * 4 * 6];// [cq][op][h2p][k] partials, 6 KB
    __shared__ float S_l[16 * 4 * 6];    // [op][h2p][k] 1.5 KB

    // stage M with the torch .view permutation undone. For h2 = 4j + h2p:
    // s = h2&1, hh = h2>>1 in {2j, 2j+1}, hp = (c2&1)*64 + hh, c = c2>>1.
    for (int i = t; i < 1536; i += 256) {
        int half = i & 1, s = (i >> 1) & 1, cc = (i >> 2) & 63, k = i >> 8;
        const float* src = ws + COEF_OFF +
            (((b * 6 + k) * 64 + cc) * 2 + s) * 128 + half * 64 + 2 * j;
        float v0 = src[0], v1 = src[1];
        int c2 = 2 * cc + half;
        float* d = M_l + (k * 128 + c2) * 4;
        d[s] = v0;           // hh=2j   -> h2p = s
        d[2 + s] = v1;       // hh=2j+1 -> h2p = 2+s
    }
    for (int i = t; i < 2048; i += 256) {
        int op = i >> 7, c2 = i & 127;
        W_l[op * 132 + c2] = fuse_w[(oq * 16 + op) * 128 + c2];
    }
    __syncthreads();

    // GEMM partials: thread = (cq = t>>6, op = (t>>2)&15, h2p = t&3),
    // acc[k] over c2 in [32cq, 32cq+32)
    int cq = t >> 6, op = (t >> 2) & 15, h2p = t & 3;
    {
        float acc[6] = {0.f, 0.f, 0.f, 0.f, 0.f, 0.f};
        const float* wrow = W_l + op * 132 + cq * 32;
        const float* mbase = M_l + (cq * 32) * 4 + h2p;
        #pragma unroll 4
        for (int c2 = 0; c2 < 32; ++c2) {
            float wv = wrow[c2];
            const float* m = mbase + c2 * 4;
            #pragma unroll
            for (int k = 0; k < 6; ++k)
                acc[k] = fmaf(wv, m[k * 512], acc[k]);
        }
        float* prow = P_l + ((cq * 16 + op) * 4 + h2p) * 6;
        #pragma unroll
        for (int k = 0; k < 6; ++k)
            prow[k] = acc[k];
    }
    __syncthreads();

    // reduce the 4 cq-partials + BN affine (threads with cq==0, i.e. t<64)
    if (cq == 0) {
        int o = oq * 16 + op;
        float scale = bn_gamma[o] * rsqrtf(bn_var[o] + 1e-5f);
        float shift = (fuse_b[o] - bn_mean[o]) * scale + bn_beta[o];
        int base = (op * 4 + h2p) * 6;
        float* srow = S_l + base;
        #pragma unroll
        for (int k = 0; k < 6; ++k) {
            float v = P_l[base + k] + P_l[384 + base + k]
                    + P_l[768 + base + k] + P_l[1152 + base + k];
            srow[k] = fmaf(v, scale, shift);
        }
    }
    __syncthreads();

    // epilogue: k->w interp + relu + store. 16*4*128 = 8192 outs, 32/thread.
    for (int it = 0; it < 32; ++it) {
        int flat = it * 256 + t;
        int w = flat & 127, row = flat >> 7;       // row = op*4 + h2p (<64)
        float pos = (float)w * (5.0f / 127.0f);
        int i0 = min((int)pos, 5);
        int i1 = min(i0 + 1, 5);
        float tt = pos - (float)i0;
        const float* srow = S_l + row * 6;
        float val = srow[i0] * (1.f - tt) + srow[i1] * tt;
        int o = oq * 16 + (row >> 2);
        int h2 = 4 * j + (row & 3);
        out[(((b * 64 + o) * 128) + h2) * 128 + w] = fmaxf(val, 0.f);
    }
}

// ---------------------------------------------------------------------------
extern "C" void kernel_launch(void* const* d_in, const int* in_sizes, int n_in,
                              void* d_out, int out_size, void* d_ws, size_t ws_size,
                              hipStream_t stream) {
    const float* x        = (const float*)d_in[0];
    const float* lin1_w   = (const float*)d_in[1];
    const float* lin1_b   = (const float*)d_in[2];
    const float* lin2_w   = (const float*)d_in[3];
    const float* lin2_b   = (const float*)d_in[4];
    const float* wf0      = (const float*)d_in[5];
    const float* wf1      = (const float*)d_in[6];
    const float* fuse_w   = (const float*)d_in[7];
    const float* fuse_b   = (const float*)d_in[8];
    const float* bn_gamma = (const float*)d_in[9];
    const float* bn_beta  = (const float*)d_in[10];
    const float* bn_mean  = (const float*)d_in[11];
    const float* bn_var   = (const float*)d_in[12];
    float* ws  = (float*)d_ws;        // needs 3.18 MB
    float* out = (float*)d_out;

    hipLaunchKernelGGL(k_pool,    dim3(BB * CC), dim3(256), 0, stream, x, ws);
    hipLaunchKernelGGL(k_radon,   dim3(BB * CC), dim3(512), 0, stream,
                       x, lin1_w, lin1_b, lin2_w, lin2_b, wf0, wf1, ws);
    hipLaunchKernelGGL(k_fuseout, dim3(1024),    dim3(256), 0, stream,
                       fuse_w, fuse_b, bn_gamma, bn_beta, bn_mean, bn_var,
                       ws, out);
}